// Round 3
// baseline (708.817 us; speedup 1.0000x reference)
//
#include <hip/hip_runtime.h>

// GIN: h1 = relu((scatter_add(x) + (1+eps0)*x) @ W0^T)
//      h2 = relu((scatter_add(h1) + (1+eps1)*h1) @ W1^T)
//      out = (h1 @ Wm^T + h2) / 2
//
// R3: CSR gather path, now latency-optimized:
//  - Wt padded [64][65]: kills the 1.6e7 staging bank-conflict cycles
//  - 512-thr blocks (8 waves share W LDS) -> 32 waves/CU possible
//  - readfirstlane(off[..]) -> bucket reads scalarize (s_load), gathers use
//    SGPR row base + shared lane*4 voffset (low VGPR)
//  - chunk-of-8 index prefetch -> 8 outstanding row gathers per wave
//  - matvec via v_readlane broadcast (no rowbuf LDS, no barriers)

#define WPB 8  // waves per 512-thread block

// ================================================================ CSR build
__global__ __launch_bounds__(256) void zero_int_kernel(int* __restrict__ p, int n)
{
    int i = blockIdx.x * blockDim.x + threadIdx.x;
    int stride = gridDim.x * blockDim.x;
    for (; i < n; i += stride) p[i] = 0;
}

__global__ __launch_bounds__(256) void hist_kernel(
    const int* __restrict__ dst, int* __restrict__ deg, int E)
{
    int e4 = (blockIdx.x * blockDim.x + threadIdx.x) * 4;
    if (e4 + 3 < E) {
        int4 d = *(const int4*)&dst[e4];
        atomicAdd(&deg[d.x], 1);
        atomicAdd(&deg[d.y], 1);
        atomicAdd(&deg[d.z], 1);
        atomicAdd(&deg[d.w], 1);
    } else {
        for (int e = e4; e < E; ++e) atomicAdd(&deg[dst[e]], 1);
    }
}

// scanA: per-block exclusive scan of 1024 elements (256 thr x 4), write block total
__global__ __launch_bounds__(256) void scanA_kernel(
    const int* __restrict__ deg, int* __restrict__ off,
    int* __restrict__ bsum, int n)
{
    __shared__ int tmp[256];
    int t = threadIdx.x;
    int base = blockIdx.x * 1024 + t * 4;
    int v0 = 0, v1 = 0, v2 = 0, v3 = 0;
    if (base + 3 < n) {
        int4 q = *(const int4*)&deg[base];
        v0 = q.x; v1 = q.y; v2 = q.z; v3 = q.w;
    } else {
        if (base + 0 < n) v0 = deg[base + 0];
        if (base + 1 < n) v1 = deg[base + 1];
        if (base + 2 < n) v2 = deg[base + 2];
    }
    int tot = v0 + v1 + v2 + v3;
    tmp[t] = tot;
    __syncthreads();
    for (int d = 1; d < 256; d <<= 1) {
        int x = (t >= d) ? tmp[t - d] : 0;
        __syncthreads();
        tmp[t] += x;
        __syncthreads();
    }
    int incl = tmp[t];
    int p = incl - tot;
    if (base + 0 < n) off[base + 0] = p;
    if (base + 1 < n) off[base + 1] = p + v0;
    if (base + 2 < n) off[base + 2] = p + v0 + v1;
    if (base + 3 < n) off[base + 3] = p + v0 + v1 + v2;
    if (t == 255) bsum[blockIdx.x] = incl;
}

__global__ __launch_bounds__(256) void scanB_kernel(int* __restrict__ bsum, int nb)
{
    __shared__ int tmp[256];
    int t = threadIdx.x;
    int v = (t < nb) ? bsum[t] : 0;
    tmp[t] = v;
    __syncthreads();
    for (int d = 1; d < 256; d <<= 1) {
        int x = (t >= d) ? tmp[t - d] : 0;
        __syncthreads();
        tmp[t] += x;
        __syncthreads();
    }
    if (t < nb) bsum[t] = tmp[t] - v;
}

__global__ __launch_bounds__(256) void scanC_kernel(
    int* __restrict__ off, int* __restrict__ cursor,
    const int* __restrict__ bsum, int n, int E)
{
    int t = threadIdx.x;
    int add = bsum[blockIdx.x];
    int base = blockIdx.x * 1024 + t * 4;
#pragma unroll
    for (int q = 0; q < 4; ++q) {
        int idx = base + q;
        if (idx < n) {
            int v = off[idx] + add;
            off[idx] = v;
            cursor[idx] = v;
        }
    }
    if (blockIdx.x == 0 && t == 0) off[n] = E;
}

__global__ __launch_bounds__(256) void fill_kernel(
    const int* __restrict__ src, const int* __restrict__ dst,
    int* __restrict__ cursor, int* __restrict__ bucket, int E)
{
    int e = blockIdx.x * blockDim.x + threadIdx.x;
    if (e < E) {
        int d = dst[e];
        int p = atomicAdd(&cursor[d], 1);
        bucket[p] = src[e];
    }
}

// ================================================================ fused gather + matvec
__device__ __forceinline__ float bcast_lane(float v, int k)
{
    return __builtin_bit_cast(float, __builtin_amdgcn_readlane(__builtin_bit_cast(int, v), k));
}

// one wave per node; lane = channel
__global__ __launch_bounds__(512, 8) void fused_gin_kernel(
    const float* __restrict__ h, const int* __restrict__ off,
    const int* __restrict__ bucket, const float* __restrict__ W,
    const float* __restrict__ eps, float* __restrict__ out, int n)
{
    __shared__ float Wt[64][65];   // Wt[k][d] = W[d][k], padded pitch: conflict-free
    int tid = threadIdx.x;
    for (int idx = tid; idx < 4096; idx += 512) Wt[idx & 63][idx >> 6] = W[idx];
    __syncthreads();
    float s = 1.0f + eps[0];
    int lane = tid & 63;
    int w = tid >> 6;
    int wavesTotal = gridDim.x * WPB;
    for (int i = blockIdx.x * WPB + w; i < n; i += wavesTotal) {
        float acc = s * h[(size_t)i * 64 + lane];
        int beg = __builtin_amdgcn_readfirstlane(off[i]);
        int end = __builtin_amdgcn_readfirstlane(off[i + 1]);
        int j = beg;
        int endc = beg + ((end - beg) & ~7);
        for (; j < endc; j += 8) {
            int s0 = bucket[j + 0], s1 = bucket[j + 1], s2 = bucket[j + 2], s3 = bucket[j + 3];
            int s4 = bucket[j + 4], s5 = bucket[j + 5], s6 = bucket[j + 6], s7 = bucket[j + 7];
            float v0 = h[(size_t)s0 * 64 + lane];
            float v1 = h[(size_t)s1 * 64 + lane];
            float v2 = h[(size_t)s2 * 64 + lane];
            float v3 = h[(size_t)s3 * 64 + lane];
            float v4 = h[(size_t)s4 * 64 + lane];
            float v5 = h[(size_t)s5 * 64 + lane];
            float v6 = h[(size_t)s6 * 64 + lane];
            float v7 = h[(size_t)s7 * 64 + lane];
            acc += ((v0 + v1) + (v2 + v3)) + ((v4 + v5) + (v6 + v7));
        }
        for (; j < end; ++j) acc += h[(size_t)bucket[j] * 64 + lane];
        float o = 0.f;
#pragma unroll
        for (int k = 0; k < 64; ++k) o += bcast_lane(acc, k) * Wt[k][lane];
        out[(size_t)i * 64 + lane] = fmaxf(o, 0.f);
    }
}

// final: out[i] = ( relu(agg(h1) @ W1^T) + h1[i] @ Wm^T ) / 2
__global__ __launch_bounds__(512, 8) void fused_final_csr_kernel(
    const float* __restrict__ h1, const int* __restrict__ off,
    const int* __restrict__ bucket, const float* __restrict__ W1,
    const float* __restrict__ Wm, const float* __restrict__ eps,
    float* __restrict__ out, int n)
{
    __shared__ float W1t[64][65];
    __shared__ float Wmt[64][65];
    int tid = threadIdx.x;
    for (int idx = tid; idx < 4096; idx += 512) {
        W1t[idx & 63][idx >> 6] = W1[idx];
        Wmt[idx & 63][idx >> 6] = Wm[idx];
    }
    __syncthreads();
    float s = 1.0f + eps[0];
    int lane = tid & 63;
    int w = tid >> 6;
    int wavesTotal = gridDim.x * WPB;
    for (int i = blockIdx.x * WPB + w; i < n; i += wavesTotal) {
        float hv = h1[(size_t)i * 64 + lane];
        float acc = s * hv;
        int beg = __builtin_amdgcn_readfirstlane(off[i]);
        int end = __builtin_amdgcn_readfirstlane(off[i + 1]);
        int j = beg;
        int endc = beg + ((end - beg) & ~7);
        for (; j < endc; j += 8) {
            int s0 = bucket[j + 0], s1 = bucket[j + 1], s2 = bucket[j + 2], s3 = bucket[j + 3];
            int s4 = bucket[j + 4], s5 = bucket[j + 5], s6 = bucket[j + 6], s7 = bucket[j + 7];
            float v0 = h1[(size_t)s0 * 64 + lane];
            float v1 = h1[(size_t)s1 * 64 + lane];
            float v2 = h1[(size_t)s2 * 64 + lane];
            float v3 = h1[(size_t)s3 * 64 + lane];
            float v4 = h1[(size_t)s4 * 64 + lane];
            float v5 = h1[(size_t)s5 * 64 + lane];
            float v6 = h1[(size_t)s6 * 64 + lane];
            float v7 = h1[(size_t)s7 * 64 + lane];
            acc += ((v0 + v1) + (v2 + v3)) + ((v4 + v5) + (v6 + v7));
        }
        for (; j < end; ++j) acc += h1[(size_t)bucket[j] * 64 + lane];
        float o1 = 0.f, o2 = 0.f;
#pragma unroll
        for (int k = 0; k < 64; ++k) {
            o1 += bcast_lane(acc, k) * W1t[k][lane];
            o2 += bcast_lane(hv, k) * Wmt[k][lane];
        }
        out[(size_t)i * 64 + lane] = (fmaxf(o1, 0.f) + o2) * 0.5f;
    }
}

// ================================================================ R1 fallback (atomic scatter)
__global__ __launch_bounds__(256) void init_scale_kernel(
    const float* __restrict__ h, const float* __restrict__ eps,
    float* __restrict__ agg, int total4)
{
    float s = 1.0f + eps[0];
    int i = blockIdx.x * blockDim.x + threadIdx.x;
    int stride = gridDim.x * blockDim.x;
    const float4* h4 = (const float4*)h;
    float4* a4 = (float4*)agg;
    for (; i < total4; i += stride) {
        float4 v = h4[i];
        v.x *= s; v.y *= s; v.z *= s; v.w *= s;
        a4[i] = v;
    }
}

__global__ __launch_bounds__(256) void scatter_kernel(
    const float* __restrict__ h, const int* __restrict__ src,
    const int* __restrict__ dst, float* __restrict__ agg, int E)
{
    int lane = threadIdx.x & 63;
    int e = blockIdx.x * 4 + (threadIdx.x >> 6);
    if (e >= E) return;
    int s = src[e];
    int d = dst[e];
    atomicAdd(&agg[(size_t)d * 64 + lane], h[(size_t)s * 64 + lane]);
}

__global__ __launch_bounds__(256) void gemm_relu_kernel(
    const float* __restrict__ A, const float* __restrict__ W,
    float* __restrict__ out, int n)
{
    __shared__ float Wt[64][65];
    int tid = threadIdx.x;
    for (int i = tid; i < 4096; i += 256) Wt[i & 63][i >> 6] = W[i];
    __syncthreads();
    int lane = tid & 63;
    int w = tid >> 6;
    int wavesTotal = gridDim.x * 4;
    for (int i = blockIdx.x * 4 + w; i < n; i += wavesTotal) {
        float a = A[(size_t)i * 64 + lane];
        float o = 0.f;
#pragma unroll
        for (int k = 0; k < 64; ++k) o += bcast_lane(a, k) * Wt[k][lane];
        out[(size_t)i * 64 + lane] = fmaxf(o, 0.f);
    }
}

__global__ __launch_bounds__(256) void final_kernel(
    const float* __restrict__ Agg, const float* __restrict__ H1,
    const float* __restrict__ W1, const float* __restrict__ Wm,
    float* __restrict__ out, int n)
{
    __shared__ float W1t[64][65];
    __shared__ float Wmt[64][65];
    int tid = threadIdx.x;
    for (int i = tid; i < 4096; i += 256) {
        W1t[i & 63][i >> 6] = W1[i];
        Wmt[i & 63][i >> 6] = Wm[i];
    }
    __syncthreads();
    int lane = tid & 63;
    int w = tid >> 6;
    int wavesTotal = gridDim.x * 4;
    for (int i = blockIdx.x * 4 + w; i < n; i += wavesTotal) {
        float a = Agg[(size_t)i * 64 + lane];
        float hv = H1[(size_t)i * 64 + lane];
        float o1 = 0.f, o2 = 0.f;
#pragma unroll
        for (int k = 0; k < 64; ++k) {
            o1 += bcast_lane(a, k) * W1t[k][lane];
            o2 += bcast_lane(hv, k) * Wmt[k][lane];
        }
        out[(size_t)i * 64 + lane] = (fmaxf(o1, 0.f) + o2) * 0.5f;
    }
}

// ================================================================ launch
extern "C" void kernel_launch(void* const* d_in, const int* in_sizes, int n_in,
                              void* d_out, int out_size, void* d_ws, size_t ws_size,
                              hipStream_t stream)
{
    const float* x    = (const float*)d_in[0];
    const int*   ei   = (const int*)d_in[1];
    const float* W0   = (const float*)d_in[2];
    const float* eps0 = (const float*)d_in[3];
    const float* W1   = (const float*)d_in[4];
    const float* eps1 = (const float*)d_in[5];
    const float* Wm   = (const float*)d_in[6];
    float* out = (float*)d_out;

    int n = in_sizes[0] / 64;   // 100000
    int E = in_sizes[1] / 2;    // 1600000
    const int* src = ei;
    const int* dst = ei + E;

    auto align1k = [](size_t v) { return (v + 1023) & ~(size_t)1023; };
    size_t h1_off     = 0;
    size_t off_off    = align1k(h1_off + (size_t)n * 64 * 4);
    size_t deg_off    = align1k(off_off + (size_t)(n + 1) * 4);
    size_t cursor_off = align1k(deg_off + (size_t)n * 4);
    size_t bsum_off   = align1k(cursor_off + (size_t)n * 4);
    size_t bucket_off = align1k(bsum_off + 256 * 4);
    size_t need       = bucket_off + (size_t)E * 4;

    if (ws_size >= need) {
        float* h1    = (float*)((char*)d_ws + h1_off);
        int* off     = (int*)((char*)d_ws + off_off);
        int* deg     = (int*)((char*)d_ws + deg_off);
        int* cursor  = (int*)((char*)d_ws + cursor_off);
        int* bsum    = (int*)((char*)d_ws + bsum_off);
        int* bucket  = (int*)((char*)d_ws + bucket_off);

        int nb = (n + 1023) / 1024;            // 98 (<=256)
        int eBlocks  = (E + 255) / 256;        // fill
        int e4Blocks = (E + 1023) / 1024;      // hist (4 edges/thread)

        zero_int_kernel<<<256, 256, 0, stream>>>(deg, n);
        hist_kernel<<<e4Blocks, 256, 0, stream>>>(dst, deg, E);
        scanA_kernel<<<nb, 256, 0, stream>>>(deg, off, bsum, n);
        scanB_kernel<<<1, 256, 0, stream>>>(bsum, nb);
        scanC_kernel<<<nb, 256, 0, stream>>>(off, cursor, bsum, n, E);
        fill_kernel<<<eBlocks, 256, 0, stream>>>(src, dst, cursor, bucket, E);

        fused_gin_kernel<<<1024, 512, 0, stream>>>(x, off, bucket, W0, eps0, h1, n);
        fused_final_csr_kernel<<<1024, 512, 0, stream>>>(h1, off, bucket, W1, Wm, eps1, out, n);
    } else {
        float* agg = (float*)d_ws;
        float* h1  = out;
        int total4 = n * 16;
        int scatterBlocks = (E + 3) / 4;

        init_scale_kernel<<<2048, 256, 0, stream>>>(x, eps0, agg, total4);
        scatter_kernel<<<scatterBlocks, 256, 0, stream>>>(x, src, dst, agg, E);
        gemm_relu_kernel<<<2048, 256, 0, stream>>>(agg, W0, h1, n);
        init_scale_kernel<<<2048, 256, 0, stream>>>(h1, eps1, agg, total4);
        scatter_kernel<<<scatterBlocks, 256, 0, stream>>>(h1, src, dst, agg, E);
        final_kernel<<<2048, 256, 0, stream>>>(agg, h1, W1, Wm, out, n);
    }
}

// Round 4
// 357.339 us; speedup vs baseline: 1.9836x; 1.9836x over previous
//
#include <hip/hip_runtime.h>

// GIN: h1 = relu((scatter_add(x) + (1+eps0)*x) @ W0^T)
//      h2 = relu((scatter_add(h1) + (1+eps1)*h1) @ W1^T)
//      out = (h1 @ Wm^T + h2) / 2
//
// R4: CSR gather path. R3's regression was __launch_bounds__(512,8) forcing a
// 32-VGPR budget -> chunk-of-8 gather values spilled to scratch (WRITE_SIZE
// 25->204MB, FETCH 189MB->1.28GB). Fix: default VGPR budget, chunk-of-4 ILP,
// 512-thr blocks (shared W LDS, 4 blocks/CU), padded Wt[64][65] (0 conflicts),
// LDS rowbuf broadcast matvec (R2-proven).

// ================================================================ CSR build
__global__ __launch_bounds__(256) void zero_int_kernel(int* __restrict__ p, int n)
{
    int i = blockIdx.x * blockDim.x + threadIdx.x;
    int stride = gridDim.x * blockDim.x;
    for (; i < n; i += stride) p[i] = 0;
}

__global__ __launch_bounds__(256) void hist_kernel(
    const int* __restrict__ dst, int* __restrict__ deg, int E)
{
    int e4 = (blockIdx.x * blockDim.x + threadIdx.x) * 4;
    if (e4 + 3 < E) {
        int4 d = *(const int4*)&dst[e4];
        atomicAdd(&deg[d.x], 1);
        atomicAdd(&deg[d.y], 1);
        atomicAdd(&deg[d.z], 1);
        atomicAdd(&deg[d.w], 1);
    } else {
        for (int e = e4; e < E; ++e) atomicAdd(&deg[dst[e]], 1);
    }
}

__global__ __launch_bounds__(256) void scanA_kernel(
    const int* __restrict__ deg, int* __restrict__ off,
    int* __restrict__ bsum, int n)
{
    __shared__ int tmp[256];
    int t = threadIdx.x;
    int base = blockIdx.x * 1024 + t * 4;
    int v0 = 0, v1 = 0, v2 = 0, v3 = 0;
    if (base + 3 < n) {
        int4 q = *(const int4*)&deg[base];
        v0 = q.x; v1 = q.y; v2 = q.z; v3 = q.w;
    } else {
        if (base + 0 < n) v0 = deg[base + 0];
        if (base + 1 < n) v1 = deg[base + 1];
        if (base + 2 < n) v2 = deg[base + 2];
    }
    int tot = v0 + v1 + v2 + v3;
    tmp[t] = tot;
    __syncthreads();
    for (int d = 1; d < 256; d <<= 1) {
        int x = (t >= d) ? tmp[t - d] : 0;
        __syncthreads();
        tmp[t] += x;
        __syncthreads();
    }
    int incl = tmp[t];
    int p = incl - tot;
    if (base + 0 < n) off[base + 0] = p;
    if (base + 1 < n) off[base + 1] = p + v0;
    if (base + 2 < n) off[base + 2] = p + v0 + v1;
    if (base + 3 < n) off[base + 3] = p + v0 + v1 + v2;
    if (t == 255) bsum[blockIdx.x] = incl;
}

__global__ __launch_bounds__(256) void scanB_kernel(int* __restrict__ bsum, int nb)
{
    __shared__ int tmp[256];
    int t = threadIdx.x;
    int v = (t < nb) ? bsum[t] : 0;
    tmp[t] = v;
    __syncthreads();
    for (int d = 1; d < 256; d <<= 1) {
        int x = (t >= d) ? tmp[t - d] : 0;
        __syncthreads();
        tmp[t] += x;
        __syncthreads();
    }
    if (t < nb) bsum[t] = tmp[t] - v;
}

__global__ __launch_bounds__(256) void scanC_kernel(
    int* __restrict__ off, int* __restrict__ cursor,
    const int* __restrict__ bsum, int n, int E)
{
    int t = threadIdx.x;
    int add = bsum[blockIdx.x];
    int base = blockIdx.x * 1024 + t * 4;
#pragma unroll
    for (int q = 0; q < 4; ++q) {
        int idx = base + q;
        if (idx < n) {
            int v = off[idx] + add;
            off[idx] = v;
            cursor[idx] = v;
        }
    }
    if (blockIdx.x == 0 && t == 0) off[n] = E;
}

__global__ __launch_bounds__(256) void fill_kernel(
    const int* __restrict__ src, const int* __restrict__ dst,
    int* __restrict__ cursor, int* __restrict__ bucket, int E)
{
    int e = blockIdx.x * blockDim.x + threadIdx.x;
    if (e < E) {
        int d = dst[e];
        int p = atomicAdd(&cursor[d], 1);
        bucket[p] = src[e];
    }
}

// ================================================================ fused gather + matvec
#define WPB 8  // waves per 512-thread block

// one wave per node; lane = channel
__global__ __launch_bounds__(512) void fused_gin_kernel(
    const float* __restrict__ h, const int* __restrict__ off,
    const int* __restrict__ bucket, const float* __restrict__ W,
    const float* __restrict__ eps, float* __restrict__ out, int n)
{
    __shared__ float Wt[64][65];       // Wt[k][d] = W[d][k], padded: conflict-free
    __shared__ float rowbuf[WPB][64];  // per-wave agg row
    int tid = threadIdx.x;
    for (int idx = tid; idx < 4096; idx += 512) Wt[idx & 63][idx >> 6] = W[idx];
    __syncthreads();
    float s = 1.0f + eps[0];
    int lane = tid & 63;
    int w = tid >> 6;
    int wavesTotal = gridDim.x * WPB;
    for (int i = blockIdx.x * WPB + w; i < n; i += wavesTotal) {
        float acc = s * h[(size_t)i * 64 + lane];
        int2 be = *(const int2*)&off[i];
        int beg = __builtin_amdgcn_readfirstlane(be.x);
        int end = __builtin_amdgcn_readfirstlane(be.y);
        int j = beg;
        int endc = beg + ((end - beg) & ~3);
        for (; j < endc; j += 4) {
            int s0 = bucket[j + 0], s1 = bucket[j + 1];
            int s2 = bucket[j + 2], s3 = bucket[j + 3];
            float v0 = h[(size_t)s0 * 64 + lane];
            float v1 = h[(size_t)s1 * 64 + lane];
            float v2 = h[(size_t)s2 * 64 + lane];
            float v3 = h[(size_t)s3 * 64 + lane];
            acc += (v0 + v1) + (v2 + v3);
        }
        for (; j < end; ++j) acc += h[(size_t)bucket[j] * 64 + lane];
        rowbuf[w][lane] = acc;
        __builtin_amdgcn_wave_barrier();
        float o = 0.f;
#pragma unroll
        for (int k = 0; k < 64; ++k) o += rowbuf[w][k] * Wt[k][lane];
        out[(size_t)i * 64 + lane] = fmaxf(o, 0.f);
        __builtin_amdgcn_wave_barrier();
    }
}

// final: out[i] = ( relu(agg(h1) @ W1^T) + h1[i] @ Wm^T ) / 2
__global__ __launch_bounds__(512) void fused_final_csr_kernel(
    const float* __restrict__ h1, const int* __restrict__ off,
    const int* __restrict__ bucket, const float* __restrict__ W1,
    const float* __restrict__ Wm, const float* __restrict__ eps,
    float* __restrict__ out, int n)
{
    __shared__ float W1t[64][65];
    __shared__ float Wmt[64][65];
    __shared__ float rowbuf[WPB][64];
    __shared__ float selfbuf[WPB][64];
    int tid = threadIdx.x;
    for (int idx = tid; idx < 4096; idx += 512) {
        W1t[idx & 63][idx >> 6] = W1[idx];
        Wmt[idx & 63][idx >> 6] = Wm[idx];
    }
    __syncthreads();
    float s = 1.0f + eps[0];
    int lane = tid & 63;
    int w = tid >> 6;
    int wavesTotal = gridDim.x * WPB;
    for (int i = blockIdx.x * WPB + w; i < n; i += wavesTotal) {
        float hv = h1[(size_t)i * 64 + lane];
        float acc = s * hv;
        int2 be = *(const int2*)&off[i];
        int beg = __builtin_amdgcn_readfirstlane(be.x);
        int end = __builtin_amdgcn_readfirstlane(be.y);
        int j = beg;
        int endc = beg + ((end - beg) & ~3);
        for (; j < endc; j += 4) {
            int s0 = bucket[j + 0], s1 = bucket[j + 1];
            int s2 = bucket[j + 2], s3 = bucket[j + 3];
            float v0 = h1[(size_t)s0 * 64 + lane];
            float v1 = h1[(size_t)s1 * 64 + lane];
            float v2 = h1[(size_t)s2 * 64 + lane];
            float v3 = h1[(size_t)s3 * 64 + lane];
            acc += (v0 + v1) + (v2 + v3);
        }
        for (; j < end; ++j) acc += h1[(size_t)bucket[j] * 64 + lane];
        rowbuf[w][lane] = acc;
        selfbuf[w][lane] = hv;
        __builtin_amdgcn_wave_barrier();
        float o1 = 0.f, o2 = 0.f;
#pragma unroll
        for (int k = 0; k < 64; ++k) {
            o1 += rowbuf[w][k] * W1t[k][lane];
            o2 += selfbuf[w][k] * Wmt[k][lane];
        }
        out[(size_t)i * 64 + lane] = (fmaxf(o1, 0.f) + o2) * 0.5f;
        __builtin_amdgcn_wave_barrier();
    }
}

// ================================================================ R1 fallback (atomic scatter)
__global__ __launch_bounds__(256) void init_scale_kernel(
    const float* __restrict__ h, const float* __restrict__ eps,
    float* __restrict__ agg, int total4)
{
    float s = 1.0f + eps[0];
    int i = blockIdx.x * blockDim.x + threadIdx.x;
    int stride = gridDim.x * blockDim.x;
    const float4* h4 = (const float4*)h;
    float4* a4 = (float4*)agg;
    for (; i < total4; i += stride) {
        float4 v = h4[i];
        v.x *= s; v.y *= s; v.z *= s; v.w *= s;
        a4[i] = v;
    }
}

__global__ __launch_bounds__(256) void scatter_kernel(
    const float* __restrict__ h, const int* __restrict__ src,
    const int* __restrict__ dst, float* __restrict__ agg, int E)
{
    int lane = threadIdx.x & 63;
    int e = blockIdx.x * 4 + (threadIdx.x >> 6);
    if (e >= E) return;
    int s = src[e];
    int d = dst[e];
    atomicAdd(&agg[(size_t)d * 64 + lane], h[(size_t)s * 64 + lane]);
}

__global__ __launch_bounds__(256) void gemm_relu_kernel(
    const float* __restrict__ A, const float* __restrict__ W,
    float* __restrict__ out, int n)
{
    __shared__ float Wt[64][65];
    __shared__ float rowbuf[4][64];
    int tid = threadIdx.x;
    for (int i = tid; i < 4096; i += 256) Wt[i & 63][i >> 6] = W[i];
    __syncthreads();
    int lane = tid & 63;
    int w = tid >> 6;
    int wavesTotal = gridDim.x * 4;
    for (int i = blockIdx.x * 4 + w; i < n; i += wavesTotal) {
        rowbuf[w][lane] = A[(size_t)i * 64 + lane];
        __builtin_amdgcn_wave_barrier();
        float o = 0.f;
#pragma unroll
        for (int k = 0; k < 64; ++k) o += rowbuf[w][k] * Wt[k][lane];
        out[(size_t)i * 64 + lane] = fmaxf(o, 0.f);
        __builtin_amdgcn_wave_barrier();
    }
}

__global__ __launch_bounds__(256) void final_kernel(
    const float* __restrict__ Agg, const float* __restrict__ H1,
    const float* __restrict__ W1, const float* __restrict__ Wm,
    float* __restrict__ out, int n)
{
    __shared__ float W1t[64][65];
    __shared__ float Wmt[64][65];
    __shared__ float rowbuf[4][64];
    __shared__ float selfbuf[4][64];
    int tid = threadIdx.x;
    for (int i = tid; i < 4096; i += 256) {
        W1t[i & 63][i >> 6] = W1[i];
        Wmt[i & 63][i >> 6] = Wm[i];
    }
    __syncthreads();
    int lane = tid & 63;
    int w = tid >> 6;
    int wavesTotal = gridDim.x * 4;
    for (int i = blockIdx.x * 4 + w; i < n; i += wavesTotal) {
        rowbuf[w][lane] = Agg[(size_t)i * 64 + lane];
        selfbuf[w][lane] = H1[(size_t)i * 64 + lane];
        __builtin_amdgcn_wave_barrier();
        float o1 = 0.f, o2 = 0.f;
#pragma unroll
        for (int k = 0; k < 64; ++k) {
            o1 += rowbuf[w][k] * W1t[k][lane];
            o2 += selfbuf[w][k] * Wmt[k][lane];
        }
        out[(size_t)i * 64 + lane] = (fmaxf(o1, 0.f) + o2) * 0.5f;
        __builtin_amdgcn_wave_barrier();
    }
}

// ================================================================ launch
extern "C" void kernel_launch(void* const* d_in, const int* in_sizes, int n_in,
                              void* d_out, int out_size, void* d_ws, size_t ws_size,
                              hipStream_t stream)
{
    const float* x    = (const float*)d_in[0];
    const int*   ei   = (const int*)d_in[1];
    const float* W0   = (const float*)d_in[2];
    const float* eps0 = (const float*)d_in[3];
    const float* W1   = (const float*)d_in[4];
    const float* eps1 = (const float*)d_in[5];
    const float* Wm   = (const float*)d_in[6];
    float* out = (float*)d_out;

    int n = in_sizes[0] / 64;   // 100000
    int E = in_sizes[1] / 2;    // 1600000
    const int* src = ei;
    const int* dst = ei + E;

    auto align1k = [](size_t v) { return (v + 1023) & ~(size_t)1023; };
    size_t h1_off     = 0;
    size_t off_off    = align1k(h1_off + (size_t)n * 64 * 4);
    size_t deg_off    = align1k(off_off + (size_t)(n + 1) * 4);
    size_t cursor_off = align1k(deg_off + (size_t)n * 4);
    size_t bsum_off   = align1k(cursor_off + (size_t)n * 4);
    size_t bucket_off = align1k(bsum_off + 256 * 4);
    size_t need       = bucket_off + (size_t)E * 4;

    if (ws_size >= need) {
        float* h1    = (float*)((char*)d_ws + h1_off);
        int* off     = (int*)((char*)d_ws + off_off);
        int* deg     = (int*)((char*)d_ws + deg_off);
        int* cursor  = (int*)((char*)d_ws + cursor_off);
        int* bsum    = (int*)((char*)d_ws + bsum_off);
        int* bucket  = (int*)((char*)d_ws + bucket_off);

        int nb = (n + 1023) / 1024;            // 98 (<=256)
        int eBlocks  = (E + 255) / 256;
        int e4Blocks = (E + 1023) / 1024;

        zero_int_kernel<<<256, 256, 0, stream>>>(deg, n);
        hist_kernel<<<e4Blocks, 256, 0, stream>>>(dst, deg, E);
        scanA_kernel<<<nb, 256, 0, stream>>>(deg, off, bsum, n);
        scanB_kernel<<<1, 256, 0, stream>>>(bsum, nb);
        scanC_kernel<<<nb, 256, 0, stream>>>(off, cursor, bsum, n, E);
        fill_kernel<<<eBlocks, 256, 0, stream>>>(src, dst, cursor, bucket, E);

        fused_gin_kernel<<<1024, 512, 0, stream>>>(x, off, bucket, W0, eps0, h1, n);
        fused_final_csr_kernel<<<1024, 512, 0, stream>>>(h1, off, bucket, W1, Wm, eps1, out, n);
    } else {
        float* agg = (float*)d_ws;
        float* h1  = out;
        int total4 = n * 16;
        int scatterBlocks = (E + 3) / 4;

        init_scale_kernel<<<2048, 256, 0, stream>>>(x, eps0, agg, total4);
        scatter_kernel<<<scatterBlocks, 256, 0, stream>>>(x, src, dst, agg, E);
        gemm_relu_kernel<<<2048, 256, 0, stream>>>(agg, W0, h1, n);
        init_scale_kernel<<<2048, 256, 0, stream>>>(h1, eps1, agg, total4);
        scatter_kernel<<<scatterBlocks, 256, 0, stream>>>(h1, src, dst, agg, E);
        final_kernel<<<2048, 256, 0, stream>>>(agg, h1, W1, Wm, out, n);
    }
}

// Round 5
// 265.831 us; speedup vs baseline: 2.6664x; 1.3442x over previous
//
#include <hip/hip_runtime.h>

// GIN: h1 = relu((scatter_add(x) + (1+eps0)*x) @ W0^T)
//      h2 = relu((scatter_add(h1) + (1+eps1)*h1) @ W1^T)
//      out = (h1 @ Wm^T + h2) / 2
//
// R5: CSR build with rank-capturing histogram.
//  - hist_rank: rank[e] = atomicAdd(&deg[dst[e]],1), 8 edges/thread (8
//    outstanding atomic round-trips; hides the return latency that made
//    R4's fill_kernel 127us at 0.3% VALUBusy)
//  - fill_rank: atomic-free scatter bucket[off[d]+rank[e]] = src[e]
//  - fused gather+matvec kernels unchanged (R4-proven)
//  - tiered ws fallback: rank path -> atomic-fill path -> R1 scatter

// ================================================================ CSR build
__global__ __launch_bounds__(256) void zero_int_kernel(int* __restrict__ p, int n)
{
    int i = blockIdx.x * blockDim.x + threadIdx.x;
    int stride = gridDim.x * blockDim.x;
    for (; i < n; i += stride) p[i] = 0;
}

// rank-capturing histogram: 8 edges/thread for MLP on returning atomics
__global__ __launch_bounds__(256) void hist_rank_kernel(
    const int* __restrict__ dst, int* __restrict__ deg,
    int* __restrict__ rank, int E)
{
    int base = (blockIdx.x * blockDim.x + threadIdx.x) * 8;
    if (base + 7 < E) {
        int4 a = *(const int4*)&dst[base];
        int4 b = *(const int4*)&dst[base + 4];
        int r0 = atomicAdd(&deg[a.x], 1);
        int r1 = atomicAdd(&deg[a.y], 1);
        int r2 = atomicAdd(&deg[a.z], 1);
        int r3 = atomicAdd(&deg[a.w], 1);
        int r4 = atomicAdd(&deg[b.x], 1);
        int r5 = atomicAdd(&deg[b.y], 1);
        int r6 = atomicAdd(&deg[b.z], 1);
        int r7 = atomicAdd(&deg[b.w], 1);
        *(int4*)&rank[base]     = make_int4(r0, r1, r2, r3);
        *(int4*)&rank[base + 4] = make_int4(r4, r5, r6, r7);
    } else {
        for (int e = base; e < E; ++e) rank[e] = atomicAdd(&deg[dst[e]], 1);
    }
}

// plain histogram (tier B)
__global__ __launch_bounds__(256) void hist_kernel(
    const int* __restrict__ dst, int* __restrict__ deg, int E)
{
    int e4 = (blockIdx.x * blockDim.x + threadIdx.x) * 4;
    if (e4 + 3 < E) {
        int4 d = *(const int4*)&dst[e4];
        atomicAdd(&deg[d.x], 1);
        atomicAdd(&deg[d.y], 1);
        atomicAdd(&deg[d.z], 1);
        atomicAdd(&deg[d.w], 1);
    } else {
        for (int e = e4; e < E; ++e) atomicAdd(&deg[dst[e]], 1);
    }
}

__global__ __launch_bounds__(256) void scanA_kernel(
    const int* __restrict__ deg, int* __restrict__ off,
    int* __restrict__ bsum, int n)
{
    __shared__ int tmp[256];
    int t = threadIdx.x;
    int base = blockIdx.x * 1024 + t * 4;
    int v0 = 0, v1 = 0, v2 = 0, v3 = 0;
    if (base + 3 < n) {
        int4 q = *(const int4*)&deg[base];
        v0 = q.x; v1 = q.y; v2 = q.z; v3 = q.w;
    } else {
        if (base + 0 < n) v0 = deg[base + 0];
        if (base + 1 < n) v1 = deg[base + 1];
        if (base + 2 < n) v2 = deg[base + 2];
    }
    int tot = v0 + v1 + v2 + v3;
    tmp[t] = tot;
    __syncthreads();
    for (int d = 1; d < 256; d <<= 1) {
        int x = (t >= d) ? tmp[t - d] : 0;
        __syncthreads();
        tmp[t] += x;
        __syncthreads();
    }
    int incl = tmp[t];
    int p = incl - tot;
    if (base + 0 < n) off[base + 0] = p;
    if (base + 1 < n) off[base + 1] = p + v0;
    if (base + 2 < n) off[base + 2] = p + v0 + v1;
    if (base + 3 < n) off[base + 3] = p + v0 + v1 + v2;
    if (t == 255) bsum[blockIdx.x] = incl;
}

__global__ __launch_bounds__(256) void scanB_kernel(int* __restrict__ bsum, int nb)
{
    __shared__ int tmp[256];
    int t = threadIdx.x;
    int v = (t < nb) ? bsum[t] : 0;
    tmp[t] = v;
    __syncthreads();
    for (int d = 1; d < 256; d <<= 1) {
        int x = (t >= d) ? tmp[t - d] : 0;
        __syncthreads();
        tmp[t] += x;
        __syncthreads();
    }
    if (t < nb) bsum[t] = tmp[t] - v;
}

// add block offsets (and optionally mirror into cursor for tier B)
__global__ __launch_bounds__(256) void scanC_kernel(
    int* __restrict__ off, int* __restrict__ cursor,
    const int* __restrict__ bsum, int n, int E)
{
    int t = threadIdx.x;
    int add = bsum[blockIdx.x];
    int base = blockIdx.x * 1024 + t * 4;
#pragma unroll
    for (int q = 0; q < 4; ++q) {
        int idx = base + q;
        if (idx < n) {
            int v = off[idx] + add;
            off[idx] = v;
            if (cursor) cursor[idx] = v;
        }
    }
    if (blockIdx.x == 0 && t == 0) off[n] = E;
}

// atomic-free fill using precomputed ranks
__global__ __launch_bounds__(256) void fill_rank_kernel(
    const int* __restrict__ src, const int* __restrict__ dst,
    const int* __restrict__ rank, const int* __restrict__ off,
    int* __restrict__ bucket, int E)
{
    int base = (blockIdx.x * blockDim.x + threadIdx.x) * 4;
    if (base + 3 < E) {
        int4 d = *(const int4*)&dst[base];
        int4 r = *(const int4*)&rank[base];
        int4 s = *(const int4*)&src[base];
        int p0 = off[d.x] + r.x;
        int p1 = off[d.y] + r.y;
        int p2 = off[d.z] + r.z;
        int p3 = off[d.w] + r.w;
        bucket[p0] = s.x;
        bucket[p1] = s.y;
        bucket[p2] = s.z;
        bucket[p3] = s.w;
    } else {
        for (int e = base; e < E; ++e) bucket[off[dst[e]] + rank[e]] = src[e];
    }
}

// tier B fill (atomic cursor)
__global__ __launch_bounds__(256) void fill_kernel(
    const int* __restrict__ src, const int* __restrict__ dst,
    int* __restrict__ cursor, int* __restrict__ bucket, int E)
{
    int e = blockIdx.x * blockDim.x + threadIdx.x;
    if (e < E) {
        int d = dst[e];
        int p = atomicAdd(&cursor[d], 1);
        bucket[p] = src[e];
    }
}

// ================================================================ fused gather + matvec
#define WPB 8  // waves per 512-thread block

__global__ __launch_bounds__(512) void fused_gin_kernel(
    const float* __restrict__ h, const int* __restrict__ off,
    const int* __restrict__ bucket, const float* __restrict__ W,
    const float* __restrict__ eps, float* __restrict__ out, int n)
{
    __shared__ float Wt[64][65];       // Wt[k][d] = W[d][k], padded: conflict-free
    __shared__ float rowbuf[WPB][64];  // per-wave agg row
    int tid = threadIdx.x;
    for (int idx = tid; idx < 4096; idx += 512) Wt[idx & 63][idx >> 6] = W[idx];
    __syncthreads();
    float s = 1.0f + eps[0];
    int lane = tid & 63;
    int w = tid >> 6;
    int wavesTotal = gridDim.x * WPB;
    for (int i = blockIdx.x * WPB + w; i < n; i += wavesTotal) {
        float acc = s * h[(size_t)i * 64 + lane];
        int2 be = *(const int2*)&off[i];
        int beg = __builtin_amdgcn_readfirstlane(be.x);
        int end = __builtin_amdgcn_readfirstlane(be.y);
        int j = beg;
        int endc = beg + ((end - beg) & ~3);
        for (; j < endc; j += 4) {
            int s0 = bucket[j + 0], s1 = bucket[j + 1];
            int s2 = bucket[j + 2], s3 = bucket[j + 3];
            float v0 = h[(size_t)s0 * 64 + lane];
            float v1 = h[(size_t)s1 * 64 + lane];
            float v2 = h[(size_t)s2 * 64 + lane];
            float v3 = h[(size_t)s3 * 64 + lane];
            acc += (v0 + v1) + (v2 + v3);
        }
        for (; j < end; ++j) acc += h[(size_t)bucket[j] * 64 + lane];
        rowbuf[w][lane] = acc;
        __builtin_amdgcn_wave_barrier();
        float o = 0.f;
#pragma unroll
        for (int k = 0; k < 64; ++k) o += rowbuf[w][k] * Wt[k][lane];
        out[(size_t)i * 64 + lane] = fmaxf(o, 0.f);
        __builtin_amdgcn_wave_barrier();
    }
}

__global__ __launch_bounds__(512) void fused_final_csr_kernel(
    const float* __restrict__ h1, const int* __restrict__ off,
    const int* __restrict__ bucket, const float* __restrict__ W1,
    const float* __restrict__ Wm, const float* __restrict__ eps,
    float* __restrict__ out, int n)
{
    __shared__ float W1t[64][65];
    __shared__ float Wmt[64][65];
    __shared__ float rowbuf[WPB][64];
    __shared__ float selfbuf[WPB][64];
    int tid = threadIdx.x;
    for (int idx = tid; idx < 4096; idx += 512) {
        W1t[idx & 63][idx >> 6] = W1[idx];
        Wmt[idx & 63][idx >> 6] = Wm[idx];
    }
    __syncthreads();
    float s = 1.0f + eps[0];
    int lane = tid & 63;
    int w = tid >> 6;
    int wavesTotal = gridDim.x * WPB;
    for (int i = blockIdx.x * WPB + w; i < n; i += wavesTotal) {
        float hv = h1[(size_t)i * 64 + lane];
        float acc = s * hv;
        int2 be = *(const int2*)&off[i];
        int beg = __builtin_amdgcn_readfirstlane(be.x);
        int end = __builtin_amdgcn_readfirstlane(be.y);
        int j = beg;
        int endc = beg + ((end - beg) & ~3);
        for (; j < endc; j += 4) {
            int s0 = bucket[j + 0], s1 = bucket[j + 1];
            int s2 = bucket[j + 2], s3 = bucket[j + 3];
            float v0 = h1[(size_t)s0 * 64 + lane];
            float v1 = h1[(size_t)s1 * 64 + lane];
            float v2 = h1[(size_t)s2 * 64 + lane];
            float v3 = h1[(size_t)s3 * 64 + lane];
            acc += (v0 + v1) + (v2 + v3);
        }
        for (; j < end; ++j) acc += h1[(size_t)bucket[j] * 64 + lane];
        rowbuf[w][lane] = acc;
        selfbuf[w][lane] = hv;
        __builtin_amdgcn_wave_barrier();
        float o1 = 0.f, o2 = 0.f;
#pragma unroll
        for (int k = 0; k < 64; ++k) {
            o1 += rowbuf[w][k] * W1t[k][lane];
            o2 += selfbuf[w][k] * Wmt[k][lane];
        }
        out[(size_t)i * 64 + lane] = (fmaxf(o1, 0.f) + o2) * 0.5f;
        __builtin_amdgcn_wave_barrier();
    }
}

// ================================================================ R1 fallback (atomic scatter)
__global__ __launch_bounds__(256) void init_scale_kernel(
    const float* __restrict__ h, const float* __restrict__ eps,
    float* __restrict__ agg, int total4)
{
    float s = 1.0f + eps[0];
    int i = blockIdx.x * blockDim.x + threadIdx.x;
    int stride = gridDim.x * blockDim.x;
    const float4* h4 = (const float4*)h;
    float4* a4 = (float4*)agg;
    for (; i < total4; i += stride) {
        float4 v = h4[i];
        v.x *= s; v.y *= s; v.z *= s; v.w *= s;
        a4[i] = v;
    }
}

__global__ __launch_bounds__(256) void scatter_kernel(
    const float* __restrict__ h, const int* __restrict__ src,
    const int* __restrict__ dst, float* __restrict__ agg, int E)
{
    int lane = threadIdx.x & 63;
    int e = blockIdx.x * 4 + (threadIdx.x >> 6);
    if (e >= E) return;
    int s = src[e];
    int d = dst[e];
    atomicAdd(&agg[(size_t)d * 64 + lane], h[(size_t)s * 64 + lane]);
}

__global__ __launch_bounds__(256) void gemm_relu_kernel(
    const float* __restrict__ A, const float* __restrict__ W,
    float* __restrict__ out, int n)
{
    __shared__ float Wt[64][65];
    __shared__ float rowbuf[4][64];
    int tid = threadIdx.x;
    for (int i = tid; i < 4096; i += 256) Wt[i & 63][i >> 6] = W[i];
    __syncthreads();
    int lane = tid & 63;
    int w = tid >> 6;
    int wavesTotal = gridDim.x * 4;
    for (int i = blockIdx.x * 4 + w; i < n; i += wavesTotal) {
        rowbuf[w][lane] = A[(size_t)i * 64 + lane];
        __builtin_amdgcn_wave_barrier();
        float o = 0.f;
#pragma unroll
        for (int k = 0; k < 64; ++k) o += rowbuf[w][k] * Wt[k][lane];
        out[(size_t)i * 64 + lane] = fmaxf(o, 0.f);
        __builtin_amdgcn_wave_barrier();
    }
}

__global__ __launch_bounds__(256) void final_kernel(
    const float* __restrict__ Agg, const float* __restrict__ H1,
    const float* __restrict__ W1, const float* __restrict__ Wm,
    float* __restrict__ out, int n)
{
    __shared__ float W1t[64][65];
    __shared__ float Wmt[64][65];
    __shared__ float rowbuf[4][64];
    __shared__ float selfbuf[4][64];
    int tid = threadIdx.x;
    for (int i = tid; i < 4096; i += 256) {
        W1t[i & 63][i >> 6] = W1[i];
        Wmt[i & 63][i >> 6] = Wm[i];
    }
    __syncthreads();
    int lane = tid & 63;
    int w = tid >> 6;
    int wavesTotal = gridDim.x * 4;
    for (int i = blockIdx.x * 4 + w; i < n; i += wavesTotal) {
        rowbuf[w][lane] = Agg[(size_t)i * 64 + lane];
        selfbuf[w][lane] = H1[(size_t)i * 64 + lane];
        __builtin_amdgcn_wave_barrier();
        float o1 = 0.f, o2 = 0.f;
#pragma unroll
        for (int k = 0; k < 64; ++k) {
            o1 += rowbuf[w][k] * W1t[k][lane];
            o2 += selfbuf[w][k] * Wmt[k][lane];
        }
        out[(size_t)i * 64 + lane] = (fmaxf(o1, 0.f) + o2) * 0.5f;
        __builtin_amdgcn_wave_barrier();
    }
}

// ================================================================ launch
extern "C" void kernel_launch(void* const* d_in, const int* in_sizes, int n_in,
                              void* d_out, int out_size, void* d_ws, size_t ws_size,
                              hipStream_t stream)
{
    const float* x    = (const float*)d_in[0];
    const int*   ei   = (const int*)d_in[1];
    const float* W0   = (const float*)d_in[2];
    const float* eps0 = (const float*)d_in[3];
    const float* W1   = (const float*)d_in[4];
    const float* eps1 = (const float*)d_in[5];
    const float* Wm   = (const float*)d_in[6];
    float* out = (float*)d_out;

    int n = in_sizes[0] / 64;   // 100000
    int E = in_sizes[1] / 2;    // 1600000
    const int* src = ei;
    const int* dst = ei + E;

    auto align1k = [](size_t v) { return (v + 1023) & ~(size_t)1023; };
    // common prefix
    size_t h1_off     = 0;
    size_t off_off    = align1k(h1_off + (size_t)n * 64 * 4);
    size_t deg_off    = align1k(off_off + (size_t)(n + 1) * 4);
    size_t cursor_off = align1k(deg_off + (size_t)n * 4);     // tier B only
    size_t bsum_off   = align1k(cursor_off + (size_t)n * 4);
    size_t bucket_off = align1k(bsum_off + 256 * 4);
    size_t rank_off   = align1k(bucket_off + (size_t)E * 4);  // tier A only
    size_t need_B     = rank_off;                              // ~33.2 MB
    size_t need_A     = rank_off + (size_t)E * 4;              // ~39.6 MB

    int nb = (n + 1023) / 1024;            // <=256 required
    int e4Blocks = (E + 1023) / 1024;      // 4 edges/thread
    int e8Blocks = (E + 2047) / 2048;      // 8 edges/thread

    if (ws_size >= need_B) {
        float* h1    = (float*)((char*)d_ws + h1_off);
        int* off     = (int*)((char*)d_ws + off_off);
        int* deg     = (int*)((char*)d_ws + deg_off);
        int* cursor  = (int*)((char*)d_ws + cursor_off);
        int* bsum    = (int*)((char*)d_ws + bsum_off);
        int* bucket  = (int*)((char*)d_ws + bucket_off);
        int* rank    = (int*)((char*)d_ws + rank_off);

        zero_int_kernel<<<256, 256, 0, stream>>>(deg, n);
        if (ws_size >= need_A) {
            // tier A: rank-capturing hist + atomic-free fill
            hist_rank_kernel<<<e8Blocks, 256, 0, stream>>>(dst, deg, rank, E);
            scanA_kernel<<<nb, 256, 0, stream>>>(deg, off, bsum, n);
            scanB_kernel<<<1, 256, 0, stream>>>(bsum, nb);
            scanC_kernel<<<nb, 256, 0, stream>>>(off, (int*)nullptr, bsum, n, E);
            fill_rank_kernel<<<e4Blocks, 256, 0, stream>>>(src, dst, rank, off, bucket, E);
        } else {
            // tier B: plain hist + atomic-cursor fill
            hist_kernel<<<e4Blocks, 256, 0, stream>>>(dst, deg, E);
            scanA_kernel<<<nb, 256, 0, stream>>>(deg, off, bsum, n);
            scanB_kernel<<<1, 256, 0, stream>>>(bsum, nb);
            scanC_kernel<<<nb, 256, 0, stream>>>(off, cursor, bsum, n, E);
            fill_kernel<<<(E + 255) / 256, 256, 0, stream>>>(src, dst, cursor, bucket, E);
        }

        fused_gin_kernel<<<1024, 512, 0, stream>>>(x, off, bucket, W0, eps0, h1, n);
        fused_final_csr_kernel<<<1024, 512, 0, stream>>>(h1, off, bucket, W1, Wm, eps1, out, n);
    } else {
        // tier C: R1 atomic scatter
        float* agg = (float*)d_ws;
        float* h1  = out;
        int total4 = n * 16;
        int scatterBlocks = (E + 3) / 4;

        init_scale_kernel<<<2048, 256, 0, stream>>>(x, eps0, agg, total4);
        scatter_kernel<<<scatterBlocks, 256, 0, stream>>>(x, src, dst, agg, E);
        gemm_relu_kernel<<<2048, 256, 0, stream>>>(agg, W0, h1, n);
        init_scale_kernel<<<2048, 256, 0, stream>>>(h1, eps1, agg, total4);
        scatter_kernel<<<scatterBlocks, 256, 0, stream>>>(h1, src, dst, agg, E);
        final_kernel<<<2048, 256, 0, stream>>>(agg, h1, W1, Wm, out, n);
    }
}

// Round 6
// 251.192 us; speedup vs baseline: 2.8218x; 1.0583x over previous
//
#include <hip/hip_runtime.h>

// GIN: h1 = relu((scatter_add(x) + (1+eps0)*x) @ W0^T)
//      h2 = relu((scatter_add(h1) + (1+eps1)*h1) @ W1^T)
//      out = (h1 @ Wm^T + h2) / 2
//
// R6: float4 gather restructure. A wave's four 16-lane groups each gather a
// DIFFERENT edge row as float4 (1 VMEM instr / 4 edges, 1KB each), partials
// reduced via LDS P[w][4][64]. Matvec reads W as per-lane rows from padded
// Ws[64][68] via ds_read_b128 (bank-optimal), row broadcast via uniform-addr
// b128. CSR build unchanged (R5-proven rank-hist + atomic-free fill).

// ================================================================ CSR build
__global__ __launch_bounds__(256) void zero_int_kernel(int* __restrict__ p, int n)
{
    int i = blockIdx.x * blockDim.x + threadIdx.x;
    int stride = gridDim.x * blockDim.x;
    for (; i < n; i += stride) p[i] = 0;
}

__global__ __launch_bounds__(256) void hist_rank_kernel(
    const int* __restrict__ dst, int* __restrict__ deg,
    int* __restrict__ rank, int E)
{
    int base = (blockIdx.x * blockDim.x + threadIdx.x) * 8;
    if (base + 7 < E) {
        int4 a = *(const int4*)&dst[base];
        int4 b = *(const int4*)&dst[base + 4];
        int r0 = atomicAdd(&deg[a.x], 1);
        int r1 = atomicAdd(&deg[a.y], 1);
        int r2 = atomicAdd(&deg[a.z], 1);
        int r3 = atomicAdd(&deg[a.w], 1);
        int r4 = atomicAdd(&deg[b.x], 1);
        int r5 = atomicAdd(&deg[b.y], 1);
        int r6 = atomicAdd(&deg[b.z], 1);
        int r7 = atomicAdd(&deg[b.w], 1);
        *(int4*)&rank[base]     = make_int4(r0, r1, r2, r3);
        *(int4*)&rank[base + 4] = make_int4(r4, r5, r6, r7);
    } else {
        for (int e = base; e < E; ++e) rank[e] = atomicAdd(&deg[dst[e]], 1);
    }
}

__global__ __launch_bounds__(256) void hist_kernel(
    const int* __restrict__ dst, int* __restrict__ deg, int E)
{
    int e4 = (blockIdx.x * blockDim.x + threadIdx.x) * 4;
    if (e4 + 3 < E) {
        int4 d = *(const int4*)&dst[e4];
        atomicAdd(&deg[d.x], 1);
        atomicAdd(&deg[d.y], 1);
        atomicAdd(&deg[d.z], 1);
        atomicAdd(&deg[d.w], 1);
    } else {
        for (int e = e4; e < E; ++e) atomicAdd(&deg[dst[e]], 1);
    }
}

__global__ __launch_bounds__(256) void scanA_kernel(
    const int* __restrict__ deg, int* __restrict__ off,
    int* __restrict__ bsum, int n)
{
    __shared__ int tmp[256];
    int t = threadIdx.x;
    int base = blockIdx.x * 1024 + t * 4;
    int v0 = 0, v1 = 0, v2 = 0, v3 = 0;
    if (base + 3 < n) {
        int4 q = *(const int4*)&deg[base];
        v0 = q.x; v1 = q.y; v2 = q.z; v3 = q.w;
    } else {
        if (base + 0 < n) v0 = deg[base + 0];
        if (base + 1 < n) v1 = deg[base + 1];
        if (base + 2 < n) v2 = deg[base + 2];
    }
    int tot = v0 + v1 + v2 + v3;
    tmp[t] = tot;
    __syncthreads();
    for (int d = 1; d < 256; d <<= 1) {
        int x = (t >= d) ? tmp[t - d] : 0;
        __syncthreads();
        tmp[t] += x;
        __syncthreads();
    }
    int incl = tmp[t];
    int p = incl - tot;
    if (base + 0 < n) off[base + 0] = p;
    if (base + 1 < n) off[base + 1] = p + v0;
    if (base + 2 < n) off[base + 2] = p + v0 + v1;
    if (base + 3 < n) off[base + 3] = p + v0 + v1 + v2;
    if (t == 255) bsum[blockIdx.x] = incl;
}

__global__ __launch_bounds__(256) void scanB_kernel(int* __restrict__ bsum, int nb)
{
    __shared__ int tmp[256];
    int t = threadIdx.x;
    int v = (t < nb) ? bsum[t] : 0;
    tmp[t] = v;
    __syncthreads();
    for (int d = 1; d < 256; d <<= 1) {
        int x = (t >= d) ? tmp[t - d] : 0;
        __syncthreads();
        tmp[t] += x;
        __syncthreads();
    }
    if (t < nb) bsum[t] = tmp[t] - v;
}

__global__ __launch_bounds__(256) void scanC_kernel(
    int* __restrict__ off, int* __restrict__ cursor,
    const int* __restrict__ bsum, int n, int E)
{
    int t = threadIdx.x;
    int add = bsum[blockIdx.x];
    int base = blockIdx.x * 1024 + t * 4;
#pragma unroll
    for (int q = 0; q < 4; ++q) {
        int idx = base + q;
        if (idx < n) {
            int v = off[idx] + add;
            off[idx] = v;
            if (cursor) cursor[idx] = v;
        }
    }
    if (blockIdx.x == 0 && t == 0) off[n] = E;
}

__global__ __launch_bounds__(256) void fill_rank_kernel(
    const int* __restrict__ src, const int* __restrict__ dst,
    const int* __restrict__ rank, const int* __restrict__ off,
    int* __restrict__ bucket, int E)
{
    int base = (blockIdx.x * blockDim.x + threadIdx.x) * 4;
    if (base + 3 < E) {
        int4 d = *(const int4*)&dst[base];
        int4 r = *(const int4*)&rank[base];
        int4 s = *(const int4*)&src[base];
        bucket[off[d.x] + r.x] = s.x;
        bucket[off[d.y] + r.y] = s.y;
        bucket[off[d.z] + r.z] = s.z;
        bucket[off[d.w] + r.w] = s.w;
    } else {
        for (int e = base; e < E; ++e) bucket[off[dst[e]] + rank[e]] = src[e];
    }
}

__global__ __launch_bounds__(256) void fill_kernel(
    const int* __restrict__ src, const int* __restrict__ dst,
    int* __restrict__ cursor, int* __restrict__ bucket, int E)
{
    int e = blockIdx.x * blockDim.x + threadIdx.x;
    if (e < E) {
        int d = dst[e];
        int p = atomicAdd(&cursor[d], 1);
        bucket[p] = src[e];
    }
}

// ================================================================ fused gather + matvec
#define WPB 8  // waves per 512-thread block

// One wave per node. Gather: 4 groups of 16 lanes, each group takes a
// different edge, float4 per lane (1 instr = 4 edges = 1KB). Matvec: lane=d
// reads its own padded W row via b128, row broadcast via uniform-addr b128.
__global__ __launch_bounds__(512) void fused_gin_kernel(
    const float* __restrict__ h, const int* __restrict__ off,
    const int* __restrict__ bucket, const float* __restrict__ W,
    const float* __restrict__ eps, float* __restrict__ out, int n)
{
    __shared__ float Ws[64][68];      // W row-major, padded (68%4==0: b128-aligned; 68%32==4: bank-spread)
    __shared__ float P[WPB][4][64];   // per-group partial rows
    __shared__ float rowbuf[WPB][64]; // reduced agg row
    int tid = threadIdx.x;
    for (int idx = tid; idx < 4096; idx += 512) Ws[idx >> 6][idx & 63] = W[idx];
    __syncthreads();
    float s = 1.0f + eps[0];
    int lane = tid & 63;
    int w = tid >> 6;
    int l16 = lane & 15;
    int g = lane >> 4;
    int wavesTotal = gridDim.x * WPB;
    for (int i = blockIdx.x * WPB + w; i < n; i += wavesTotal) {
        // self row folded into group 0's partial
        float4 self4 = *(const float4*)&h[(size_t)i * 64 + l16 * 4];
        float4 acc4;
        if (g == 0) acc4 = make_float4(s * self4.x, s * self4.y, s * self4.z, s * self4.w);
        else        acc4 = make_float4(0.f, 0.f, 0.f, 0.f);

        int2 be = *(const int2*)&off[i];
        int beg = __builtin_amdgcn_readfirstlane(be.x);
        int end = __builtin_amdgcn_readfirstlane(be.y);
        int j = beg;
        for (; j + 8 <= end; j += 8) {   // 8 edges: 2 independent 1KB gathers
            int sa = bucket[j + g];
            int sb = bucket[j + 4 + g];
            float4 va = *(const float4*)&h[(size_t)sa * 64 + l16 * 4];
            float4 vb = *(const float4*)&h[(size_t)sb * 64 + l16 * 4];
            acc4.x += va.x + vb.x;
            acc4.y += va.y + vb.y;
            acc4.z += va.z + vb.z;
            acc4.w += va.w + vb.w;
        }
        if (j + 4 <= end) {
            int sa = bucket[j + g];
            float4 va = *(const float4*)&h[(size_t)sa * 64 + l16 * 4];
            acc4.x += va.x; acc4.y += va.y; acc4.z += va.z; acc4.w += va.w;
            j += 4;
        }
        if (j < end) {                    // 1..3 tail edges: clamp + mask
            int jj = j + g;
            int sc = bucket[(jj < end) ? jj : (end - 1)];
            float m = (jj < end) ? 1.0f : 0.0f;
            float4 vc = *(const float4*)&h[(size_t)sc * 64 + l16 * 4];
            acc4.x = fmaf(vc.x, m, acc4.x);
            acc4.y = fmaf(vc.y, m, acc4.y);
            acc4.z = fmaf(vc.z, m, acc4.z);
            acc4.w = fmaf(vc.w, m, acc4.w);
        }
        *(float4*)&P[w][g][l16 * 4] = acc4;
        __builtin_amdgcn_wave_barrier();
        float r0 = P[w][0][lane], r1 = P[w][1][lane];
        float r2 = P[w][2][lane], r3 = P[w][3][lane];
        rowbuf[w][lane] = (r0 + r1) + (r2 + r3);
        __builtin_amdgcn_wave_barrier();
        // matvec: out[lane] = sum_k row[k] * W[lane][k]
        const float4* wrow = (const float4*)&Ws[lane][0];
        const float4* rrow = (const float4*)&rowbuf[w][0];
        float o = 0.f;
#pragma unroll
        for (int k4 = 0; k4 < 16; ++k4) {
            float4 ww = wrow[k4];
            float4 rr = rrow[k4];
            o += ww.x * rr.x + ww.y * rr.y + ww.z * rr.z + ww.w * rr.w;
        }
        out[(size_t)i * 64 + lane] = fmaxf(o, 0.f);
        __builtin_amdgcn_wave_barrier();
    }
}

// final: out[i] = ( relu(agg(h1) @ W1^T) + h1[i] @ Wm^T ) / 2
__global__ __launch_bounds__(512) void fused_final_csr_kernel(
    const float* __restrict__ h1, const int* __restrict__ off,
    const int* __restrict__ bucket, const float* __restrict__ W1,
    const float* __restrict__ Wm, const float* __restrict__ eps,
    float* __restrict__ out, int n)
{
    __shared__ float W1s[64][68];
    __shared__ float Wms[64][68];
    __shared__ float P[WPB][4][64];
    __shared__ float rowbuf[WPB][64];
    __shared__ float selfbuf[WPB][64];
    int tid = threadIdx.x;
    for (int idx = tid; idx < 4096; idx += 512) {
        W1s[idx >> 6][idx & 63] = W1[idx];
        Wms[idx >> 6][idx & 63] = Wm[idx];
    }
    __syncthreads();
    float s = 1.0f + eps[0];
    int lane = tid & 63;
    int w = tid >> 6;
    int l16 = lane & 15;
    int g = lane >> 4;
    int wavesTotal = gridDim.x * WPB;
    for (int i = blockIdx.x * WPB + w; i < n; i += wavesTotal) {
        float4 self4 = *(const float4*)&h1[(size_t)i * 64 + l16 * 4];
        float4 acc4;
        if (g == 0) acc4 = make_float4(s * self4.x, s * self4.y, s * self4.z, s * self4.w);
        else        acc4 = make_float4(0.f, 0.f, 0.f, 0.f);
        if (g == 0) *(float4*)&selfbuf[w][l16 * 4] = self4;

        int2 be = *(const int2*)&off[i];
        int beg = __builtin_amdgcn_readfirstlane(be.x);
        int end = __builtin_amdgcn_readfirstlane(be.y);
        int j = beg;
        for (; j + 8 <= end; j += 8) {
            int sa = bucket[j + g];
            int sb = bucket[j + 4 + g];
            float4 va = *(const float4*)&h1[(size_t)sa * 64 + l16 * 4];
            float4 vb = *(const float4*)&h1[(size_t)sb * 64 + l16 * 4];
            acc4.x += va.x + vb.x;
            acc4.y += va.y + vb.y;
            acc4.z += va.z + vb.z;
            acc4.w += va.w + vb.w;
        }
        if (j + 4 <= end) {
            int sa = bucket[j + g];
            float4 va = *(const float4*)&h1[(size_t)sa * 64 + l16 * 4];
            acc4.x += va.x; acc4.y += va.y; acc4.z += va.z; acc4.w += va.w;
            j += 4;
        }
        if (j < end) {
            int jj = j + g;
            int sc = bucket[(jj < end) ? jj : (end - 1)];
            float m = (jj < end) ? 1.0f : 0.0f;
            float4 vc = *(const float4*)&h1[(size_t)sc * 64 + l16 * 4];
            acc4.x = fmaf(vc.x, m, acc4.x);
            acc4.y = fmaf(vc.y, m, acc4.y);
            acc4.z = fmaf(vc.z, m, acc4.z);
            acc4.w = fmaf(vc.w, m, acc4.w);
        }
        *(float4*)&P[w][g][l16 * 4] = acc4;
        __builtin_amdgcn_wave_barrier();
        float r0 = P[w][0][lane], r1 = P[w][1][lane];
        float r2 = P[w][2][lane], r3 = P[w][3][lane];
        rowbuf[w][lane] = (r0 + r1) + (r2 + r3);
        __builtin_amdgcn_wave_barrier();
        const float4* w1row = (const float4*)&W1s[lane][0];
        const float4* wmrow = (const float4*)&Wms[lane][0];
        const float4* rrow  = (const float4*)&rowbuf[w][0];
        const float4* srow  = (const float4*)&selfbuf[w][0];
        float o1 = 0.f, o2 = 0.f;
#pragma unroll
        for (int k4 = 0; k4 < 16; ++k4) {
            float4 w1 = w1row[k4];
            float4 wm = wmrow[k4];
            float4 rr = rrow[k4];
            float4 sv = srow[k4];
            o1 += w1.x * rr.x + w1.y * rr.y + w1.z * rr.z + w1.w * rr.w;
            o2 += wm.x * sv.x + wm.y * sv.y + wm.z * sv.z + wm.w * sv.w;
        }
        out[(size_t)i * 64 + lane] = (fmaxf(o1, 0.f) + o2) * 0.5f;
        __builtin_amdgcn_wave_barrier();
    }
}

// ================================================================ R1 fallback (atomic scatter)
__global__ __launch_bounds__(256) void init_scale_kernel(
    const float* __restrict__ h, const float* __restrict__ eps,
    float* __restrict__ agg, int total4)
{
    float s = 1.0f + eps[0];
    int i = blockIdx.x * blockDim.x + threadIdx.x;
    int stride = gridDim.x * blockDim.x;
    const float4* h4 = (const float4*)h;
    float4* a4 = (float4*)agg;
    for (; i < total4; i += stride) {
        float4 v = h4[i];
        v.x *= s; v.y *= s; v.z *= s; v.w *= s;
        a4[i] = v;
    }
}

__global__ __launch_bounds__(256) void scatter_kernel(
    const float* __restrict__ h, const int* __restrict__ src,
    const int* __restrict__ dst, float* __restrict__ agg, int E)
{
    int lane = threadIdx.x & 63;
    int e = blockIdx.x * 4 + (threadIdx.x >> 6);
    if (e >= E) return;
    int s = src[e];
    int d = dst[e];
    atomicAdd(&agg[(size_t)d * 64 + lane], h[(size_t)s * 64 + lane]);
}

__global__ __launch_bounds__(256) void gemm_relu_kernel(
    const float* __restrict__ A, const float* __restrict__ W,
    float* __restrict__ out, int n)
{
    __shared__ float Wt[64][65];
    __shared__ float rowbuf[4][64];
    int tid = threadIdx.x;
    for (int i = tid; i < 4096; i += 256) Wt[i & 63][i >> 6] = W[i];
    __syncthreads();
    int lane = tid & 63;
    int w = tid >> 6;
    int wavesTotal = gridDim.x * 4;
    for (int i = blockIdx.x * 4 + w; i < n; i += wavesTotal) {
        rowbuf[w][lane] = A[(size_t)i * 64 + lane];
        __builtin_amdgcn_wave_barrier();
        float o = 0.f;
#pragma unroll
        for (int k = 0; k < 64; ++k) o += rowbuf[w][k] * Wt[k][lane];
        out[(size_t)i * 64 + lane] = fmaxf(o, 0.f);
        __builtin_amdgcn_wave_barrier();
    }
}

__global__ __launch_bounds__(256) void final_kernel(
    const float* __restrict__ Agg, const float* __restrict__ H1,
    const float* __restrict__ W1, const float* __restrict__ Wm,
    float* __restrict__ out, int n)
{
    __shared__ float W1t[64][65];
    __shared__ float Wmt[64][65];
    __shared__ float rowbuf[4][64];
    __shared__ float selfbuf[4][64];
    int tid = threadIdx.x;
    for (int i = tid; i < 4096; i += 256) {
        W1t[i & 63][i >> 6] = W1[i];
        Wmt[i & 63][i >> 6] = Wm[i];
    }
    __syncthreads();
    int lane = tid & 63;
    int w = tid >> 6;
    int wavesTotal = gridDim.x * 4;
    for (int i = blockIdx.x * 4 + w; i < n; i += wavesTotal) {
        rowbuf[w][lane] = Agg[(size_t)i * 64 + lane];
        selfbuf[w][lane] = H1[(size_t)i * 64 + lane];
        __builtin_amdgcn_wave_barrier();
        float o1 = 0.f, o2 = 0.f;
#pragma unroll
        for (int k = 0; k < 64; ++k) {
            o1 += rowbuf[w][k] * W1t[k][lane];
            o2 += selfbuf[w][k] * Wmt[k][lane];
        }
        out[(size_t)i * 64 + lane] = (fmaxf(o1, 0.f) + o2) * 0.5f;
        __builtin_amdgcn_wave_barrier();
    }
}

// ================================================================ launch
extern "C" void kernel_launch(void* const* d_in, const int* in_sizes, int n_in,
                              void* d_out, int out_size, void* d_ws, size_t ws_size,
                              hipStream_t stream)
{
    const float* x    = (const float*)d_in[0];
    const int*   ei   = (const int*)d_in[1];
    const float* W0   = (const float*)d_in[2];
    const float* eps0 = (const float*)d_in[3];
    const float* W1   = (const float*)d_in[4];
    const float* eps1 = (const float*)d_in[5];
    const float* Wm   = (const float*)d_in[6];
    float* out = (float*)d_out;

    int n = in_sizes[0] / 64;   // 100000
    int E = in_sizes[1] / 2;    // 1600000
    const int* src = ei;
    const int* dst = ei + E;

    auto align1k = [](size_t v) { return (v + 1023) & ~(size_t)1023; };
    size_t h1_off     = 0;
    size_t off_off    = align1k(h1_off + (size_t)n * 64 * 4);
    size_t deg_off    = align1k(off_off + (size_t)(n + 1) * 4);
    size_t cursor_off = align1k(deg_off + (size_t)n * 4);
    size_t bsum_off   = align1k(cursor_off + (size_t)n * 4);
    size_t bucket_off = align1k(bsum_off + 256 * 4);
    size_t rank_off   = align1k(bucket_off + (size_t)E * 4);
    size_t need_B     = rank_off;                  // ~33.2 MB
    size_t need_A     = rank_off + (size_t)E * 4;  // ~39.6 MB

    int nb = (n + 1023) / 1024;
    int e4Blocks = (E + 1023) / 1024;
    int e8Blocks = (E + 2047) / 2048;

    if (ws_size >= need_B) {
        float* h1    = (float*)((char*)d_ws + h1_off);
        int* off     = (int*)((char*)d_ws + off_off);
        int* deg     = (int*)((char*)d_ws + deg_off);
        int* cursor  = (int*)((char*)d_ws + cursor_off);
        int* bsum    = (int*)((char*)d_ws + bsum_off);
        int* bucket  = (int*)((char*)d_ws + bucket_off);
        int* rank    = (int*)((char*)d_ws + rank_off);

        zero_int_kernel<<<256, 256, 0, stream>>>(deg, n);
        if (ws_size >= need_A) {
            hist_rank_kernel<<<e8Blocks, 256, 0, stream>>>(dst, deg, rank, E);
            scanA_kernel<<<nb, 256, 0, stream>>>(deg, off, bsum, n);
            scanB_kernel<<<1, 256, 0, stream>>>(bsum, nb);
            scanC_kernel<<<nb, 256, 0, stream>>>(off, (int*)nullptr, bsum, n, E);
            fill_rank_kernel<<<e4Blocks, 256, 0, stream>>>(src, dst, rank, off, bucket, E);
        } else {
            hist_kernel<<<e4Blocks, 256, 0, stream>>>(dst, deg, E);
            scanA_kernel<<<nb, 256, 0, stream>>>(deg, off, bsum, n);
            scanB_kernel<<<1, 256, 0, stream>>>(bsum, nb);
            scanC_kernel<<<nb, 256, 0, stream>>>(off, cursor, bsum, n, E);
            fill_kernel<<<(E + 255) / 256, 256, 0, stream>>>(src, dst, cursor, bucket, E);
        }

        // gin: 27.6KB LDS -> 4 blocks/CU (wave-cap) -> grid 1024
        fused_gin_kernel<<<1024, 512, 0, stream>>>(x, off, bucket, W0, eps0, h1, n);
        // final: 47.1KB LDS -> 3 blocks/CU -> grid 768
        fused_final_csr_kernel<<<768, 512, 0, stream>>>(h1, off, bucket, W1, Wm, eps1, out, n);
    } else {
        float* agg = (float*)d_ws;
        float* h1  = out;
        int total4 = n * 16;
        int scatterBlocks = (E + 3) / 4;

        init_scale_kernel<<<2048, 256, 0, stream>>>(x, eps0, agg, total4);
        scatter_kernel<<<scatterBlocks, 256, 0, stream>>>(x, src, dst, agg, E);
        gemm_relu_kernel<<<2048, 256, 0, stream>>>(agg, W0, h1, n);
        init_scale_kernel<<<2048, 256, 0, stream>>>(h1, eps1, agg, total4);
        scatter_kernel<<<scatterBlocks, 256, 0, stream>>>(h1, src, dst, agg, E);
        final_kernel<<<2048, 256, 0, stream>>>(agg, h1, W1, Wm, out, n);
    }
}